// Round 1
// baseline (362.441 us; speedup 1.0000x reference)
//
#include <hip/hip_runtime.h>
#include <hip/hip_bf16.h>

#define NEXP 8
#define NEMB 1024
#define NTOK 8192
#define BM 128
#define BN 128
#define BK 64

typedef __attribute__((ext_vector_type(8))) short  bf16x8;
typedef __attribute__((ext_vector_type(8))) unsigned short u16x8;
typedef __attribute__((ext_vector_type(4))) float  f32x4;

// ---- workspace layout (bytes) ----
// xb   : NTOK*NEMB*2          = 16,777,216
// wb   : NEXP*NEMB*NEMB*2     = 16,777,216
// cnt  : 8*4 (aligned to 256)
// ltok : NEXP*NTOK*4          = 262,144
// lwt  : NEXP*NTOK*4          = 262,144
#define XB_BYTES  (NTOK * NEMB * 2)
#define WB_BYTES  (NEXP * NEMB * NEMB * 2)
#define CNT_OFF   (XB_BYTES + WB_BYTES)
#define LTOK_OFF  (CNT_OFF + 256)
#define LWT_OFF   (LTOK_OFF + NEXP * NTOK * 4)

__device__ __forceinline__ unsigned short f2bf(float f) {
    unsigned u = __builtin_bit_cast(unsigned, f);
    unsigned r = (u + 0x7fffu + ((u >> 16) & 1u)) >> 16;
    return (unsigned short)r;
}

// ---------------- expert_w fp32 -> bf16 ----------------
__global__ void k_cvt_w(const float* __restrict__ w, unsigned short* __restrict__ wb) {
    int i = (blockIdx.x * blockDim.x + threadIdx.x) * 8;   // 8 elems / thread
    f32x4 v0 = *reinterpret_cast<const f32x4*>(w + i);
    f32x4 v1 = *reinterpret_cast<const f32x4*>(w + i + 4);
    u16x8 o;
#pragma unroll
    for (int j = 0; j < 4; ++j) { o[j] = f2bf(v0[j]); o[4 + j] = f2bf(v1[j]); }
    *reinterpret_cast<u16x8*>(wb + i) = o;
}

// ---------------- gating: logits, top-2, softmax, routing lists, x->bf16 ----------------
__global__ void k_gate(const float* __restrict__ x, const float* __restrict__ gw,
                       unsigned short* __restrict__ xb, int* __restrict__ counts,
                       int* __restrict__ ltok, float* __restrict__ lwt) {
    __shared__ float gs[NEXP * NEMB];          // 32 KB
    int t = threadIdx.x;
    for (int i = t; i < NEXP * NEMB / 4; i += 256)
        reinterpret_cast<f32x4*>(gs)[i] = reinterpret_cast<const f32x4*>(gw)[i];
    __syncthreads();

    int wave = t >> 6, lane = t & 63;
    int tok0 = (blockIdx.x * 4 + wave) * 8;    // 8 tokens per wave

    for (int it = 0; it < 8; ++it) {
        int n = tok0 + it;
        const float* xr = x + (size_t)n * NEMB;
        float p[NEXP];
#pragma unroll
        for (int e = 0; e < NEXP; ++e) p[e] = 0.f;
        unsigned short xv16[16];
#pragma unroll
        for (int j = 0; j < 16; ++j) {
            float xv = xr[j * 64 + lane];
            xv16[j] = f2bf(xv);
#pragma unroll
            for (int e = 0; e < NEXP; ++e) p[e] += xv * gs[e * NEMB + j * 64 + lane];
        }
#pragma unroll
        for (int j = 0; j < 16; ++j) xb[(size_t)n * NEMB + j * 64 + lane] = xv16[j];
        // butterfly reduce each logit across 64 lanes
#pragma unroll
        for (int e = 0; e < NEXP; ++e) {
            float v = p[e];
#pragma unroll
            for (int m = 1; m < 64; m <<= 1) v += __shfl_xor(v, m, 64);
            p[e] = v;
        }
        // top-2 (strict > => lowest index wins ties, matches lax.top_k)
        int e0 = 0; float b0 = p[0];
#pragma unroll
        for (int e = 1; e < NEXP; ++e) if (p[e] > b0) { b0 = p[e]; e0 = e; }
        int e1 = -1; float b1 = -3.4e38f;
#pragma unroll
        for (int e = 0; e < NEXP; ++e) if (e != e0 && p[e] > b1) { b1 = p[e]; e1 = e; }
        float ex = __expf(b1 - b0);          // <= 1
        float inv = 1.f / (1.f + ex);
        float w0 = inv, w1 = ex * inv;
        if (lane == 0) {
            int p0 = atomicAdd(&counts[e0], 1);
            ltok[e0 * NTOK + p0] = n; lwt[e0 * NTOK + p0] = w0;
            int p1 = atomicAdd(&counts[e1], 1);
            ltok[e1 * NTOK + p1] = n; lwt[e1 * NTOK + p1] = w1;
        }
    }
}

// ---------------- pad lists up to multiple of BM with (token 0, weight 0) ----------------
__global__ void k_pad(const int* __restrict__ counts, int* __restrict__ ltok,
                      float* __restrict__ lwt) {
    int e = blockIdx.x;
    int c = counts[e];
    int cp = (c + BM - 1) & ~(BM - 1);
    for (int i = c + threadIdx.x; i < cp; i += blockDim.x) {
        ltok[e * NTOK + i] = 0;
        lwt[e * NTOK + i] = 0.f;
    }
}

// ---------------- grouped gathered GEMM: out[tok, :] += w * xb[tok,:] @ Wb_e^T ----------------
__global__ __launch_bounds__(256)
void k_gemm(const unsigned short* __restrict__ xb, const unsigned short* __restrict__ wb,
            const int* __restrict__ counts, const int* __restrict__ ltok,
            const float* __restrict__ lwt, float* __restrict__ out) {
    int e = blockIdx.z;
    int cnt = counts[e];
    int rb = blockIdx.y;
    if (rb * BM >= cnt) return;
    int cb = blockIdx.x;

    __shared__ unsigned short As[BM * BK];   // 16 KB, row-major [row][64]
    __shared__ unsigned short Bs[BN * BK];   // 16 KB
    __shared__ int   tokS[BM];
    __shared__ float wS[BM];

    int t = threadIdx.x;
    int lane = t & 63, wave = t >> 6;
    int wr = wave >> 1, wc = wave & 1;

    if (t < BM) {
        tokS[t] = ltok[e * NTOK + rb * BM + t];
        wS[t]   = lwt[e * NTOK + rb * BM + t];
    }

    // per-thread staging sources (4 chunks of 16B for A, 4 for B)
    const unsigned short* aSrc[4];
    const unsigned short* bSrc[4];
#pragma unroll
    for (int i = 0; i < 4; ++i) {
        int idx = i * 256 + t;          // 16B chunk index in the 128x64 tile
        int r   = idx >> 3;             // row 0..127
        int c8  = (idx & 7) * 8;        // col in elems
        int tok = ltok[e * NTOK + rb * BM + r];
        aSrc[i] = xb + (size_t)tok * NEMB + c8;
        bSrc[i] = wb + (size_t)e * NEMB * NEMB + (size_t)(cb * BN + r) * NEMB + c8;
    }

    f32x4 acc[4][4];
#pragma unroll
    for (int m = 0; m < 4; ++m)
#pragma unroll
        for (int n = 0; n < 4; ++n) acc[m][n] = (f32x4){0.f, 0.f, 0.f, 0.f};

    int fr = lane & 15, fq = lane >> 4;
    const unsigned short* Abase = As + (wr * 64 + fr) * BK + fq * 8;
    const unsigned short* Bbase = Bs + (wc * 64 + fr) * BK + fq * 8;

    for (int kk = 0; kk < NEMB / BK; ++kk) {
#pragma unroll
        for (int i = 0; i < 4; ++i) {
            int ldso = (i * 256 + wave * 64) * 8;   // wave-uniform LDS elem offset
            __builtin_amdgcn_global_load_lds(
                (const __attribute__((address_space(1))) void*)(aSrc[i]),
                (__attribute__((address_space(3))) void*)(As + ldso), 16, 0, 0);
            __builtin_amdgcn_global_load_lds(
                (const __attribute__((address_space(1))) void*)(bSrc[i]),
                (__attribute__((address_space(3))) void*)(Bs + ldso), 16, 0, 0);
        }
        __syncthreads();
#pragma unroll
        for (int ks = 0; ks < 2; ++ks) {
            bf16x8 af[4], bfr[4];
#pragma unroll
            for (int m = 0; m < 4; ++m)
                af[m] = *reinterpret_cast<const bf16x8*>(Abase + m * 16 * BK + ks * 32);
#pragma unroll
            for (int n = 0; n < 4; ++n)
                bfr[n] = *reinterpret_cast<const bf16x8*>(Bbase + n * 16 * BK + ks * 32);
#pragma unroll
            for (int m = 0; m < 4; ++m)
#pragma unroll
                for (int n = 0; n < 4; ++n)
                    acc[m][n] = __builtin_amdgcn_mfma_f32_16x16x32_bf16(
                        af[m], bfr[n], acc[m][n], 0, 0, 0);
        }
        __syncthreads();
#pragma unroll
        for (int i = 0; i < 4; ++i) { aSrc[i] += BK; bSrc[i] += BK; }
    }

    // epilogue: out[tok, cb*BN + wc*64 + n*16 + fr] += w * acc
#pragma unroll
    for (int m = 0; m < 4; ++m) {
#pragma unroll
        for (int jj = 0; jj < 4; ++jj) {
            int row  = wr * 64 + m * 16 + fq * 4 + jj;
            int tok  = tokS[row];
            float wgt = wS[row];
            float* orow = out + (size_t)tok * NEMB + cb * BN + wc * 64 + fr;
#pragma unroll
            for (int n = 0; n < 4; ++n)
                unsafeAtomicAdd(orow + n * 16, wgt * acc[m][n][jj]);
        }
    }
}

extern "C" void kernel_launch(void* const* d_in, const int* in_sizes, int n_in,
                              void* d_out, int out_size, void* d_ws, size_t ws_size,
                              hipStream_t stream) {
    const float* x  = (const float*)d_in[0];
    const float* gw = (const float*)d_in[1];
    const float* ew = (const float*)d_in[2];
    float* out = (float*)d_out;

    char* ws = (char*)d_ws;
    unsigned short* xb  = (unsigned short*)(ws);
    unsigned short* wb  = (unsigned short*)(ws + XB_BYTES);
    int*   counts = (int*)(ws + CNT_OFF);
    int*   ltok   = (int*)(ws + LTOK_OFF);
    float* lwt    = (float*)(ws + LWT_OFF);

    hipMemsetAsync(counts, 0, 8 * sizeof(int), stream);
    hipMemsetAsync(out, 0, (size_t)NTOK * NEMB * sizeof(float), stream);

    // expert_w -> bf16 : 8*1024*1024 / 8 per thread / 256 = 4096 blocks
    k_cvt_w<<<4096, 256, 0, stream>>>(ew, wb);
    // gating + x->bf16 + routing lists
    k_gate<<<256, 256, 0, stream>>>(x, gw, xb, counts, ltok, lwt);
    // pad each expert's list to a multiple of BM
    k_pad<<<8, 128, 0, stream>>>(counts, ltok, lwt);
    // grouped gathered GEMM with weighted atomic scatter
    k_gemm<<<dim3(NEMB / BN, NTOK / BM, NEXP), 256, 0, stream>>>(xb, wb, counts, ltok, lwt, out);
}

// Round 2
// 353.239 us; speedup vs baseline: 1.0261x; 1.0261x over previous
//
#include <hip/hip_runtime.h>
#include <hip/hip_bf16.h>

#define NEXP 8
#define NEMB 1024
#define NTOK 8192
#define BM 128
#define BN 128
#define BK 64
#define TPW 4   // tokens per wave in k_gate

typedef __attribute__((ext_vector_type(8))) short  bf16x8;
typedef __attribute__((ext_vector_type(8))) unsigned short u16x8;
typedef __attribute__((ext_vector_type(4))) float  f32x4;

// ---- workspace layout (bytes) ----
#define XB_BYTES  (NTOK * NEMB * 2)
#define WB_BYTES  (NEXP * NEMB * NEMB * 2)
#define CNT_OFF   (XB_BYTES + WB_BYTES)
#define LTOK_OFF  (CNT_OFF + 256)
#define LWT_OFF   (LTOK_OFF + NEXP * NTOK * 4)

__device__ __forceinline__ unsigned short f2bf(float f) {
    unsigned u = __builtin_bit_cast(unsigned, f);
    unsigned r = (u + 0x7fffu + ((u >> 16) & 1u)) >> 16;
    return (unsigned short)r;
}

// ---------------- expert_w fp32 -> bf16 ----------------
__global__ void k_cvt_w(const float* __restrict__ w, unsigned short* __restrict__ wb) {
    int i = (blockIdx.x * blockDim.x + threadIdx.x) * 8;   // 8 elems / thread
    f32x4 v0 = *reinterpret_cast<const f32x4*>(w + i);
    f32x4 v1 = *reinterpret_cast<const f32x4*>(w + i + 4);
    u16x8 o;
#pragma unroll
    for (int j = 0; j < 4; ++j) { o[j] = f2bf(v0[j]); o[4 + j] = f2bf(v1[j]); }
    *reinterpret_cast<u16x8*>(wb + i) = o;
}

// ---------------- gating: logits (fp32 exact), top-2, softmax, lists, x->bf16 ----------------
// 1 token per wave-iteration, TPW tokens per wave; gw held in registers.
__global__ __launch_bounds__(256)
void k_gate(const float* __restrict__ x, const float* __restrict__ gw,
            unsigned short* __restrict__ xb, int* __restrict__ counts,
            int* __restrict__ ltok, float* __restrict__ lwt) {
    int t = threadIdx.x, wave = t >> 6, lane = t & 63;

    // lane l owns elements [l*16, l*16+16) of each gate row
    f32x4 g[NEXP][4];
#pragma unroll
    for (int e = 0; e < NEXP; ++e)
#pragma unroll
        for (int j = 0; j < 4; ++j)
            g[e][j] = *reinterpret_cast<const f32x4*>(gw + e * NEMB + lane * 16 + j * 4);

    int tok0 = (blockIdx.x * 4 + wave) * TPW;

#pragma unroll
    for (int it = 0; it < TPW; ++it) {
        int n = tok0 + it;
        const float* xr = x + (size_t)n * NEMB + lane * 16;
        f32x4 xv[4];
#pragma unroll
        for (int j = 0; j < 4; ++j) xv[j] = *reinterpret_cast<const f32x4*>(xr + j * 4);

        // x -> bf16 (16B vector stores)
        u16x8 o0, o1;
#pragma unroll
        for (int q = 0; q < 4; ++q) {
            o0[q]     = f2bf(xv[0][q]); o0[4 + q] = f2bf(xv[1][q]);
            o1[q]     = f2bf(xv[2][q]); o1[4 + q] = f2bf(xv[3][q]);
        }
        u16x8* xo = reinterpret_cast<u16x8*>(xb + (size_t)n * NEMB + lane * 16);
        xo[0] = o0; xo[1] = o1;

        // partial logits
        float p[NEXP];
#pragma unroll
        for (int e = 0; e < NEXP; ++e) {
            f32x4 a = xv[0] * g[e][0];
#pragma unroll
            for (int j = 1; j < 4; ++j) a += xv[j] * g[e][j];
            p[e] = a[0] + a[1] + a[2] + a[3];
        }
        // butterfly reduce across 64 lanes
#pragma unroll
        for (int e = 0; e < NEXP; ++e) {
            float v = p[e];
#pragma unroll
            for (int m = 1; m < 64; m <<= 1) v += __shfl_xor(v, m, 64);
            p[e] = v;
        }
        // top-2, lowest index wins ties (matches lax.top_k)
        int e0 = 0; float b0 = p[0];
#pragma unroll
        for (int e = 1; e < NEXP; ++e) if (p[e] > b0) { b0 = p[e]; e0 = e; }
        int e1 = -1; float b1 = -3.4e38f;
#pragma unroll
        for (int e = 0; e < NEXP; ++e) if (e != e0 && p[e] > b1) { b1 = p[e]; e1 = e; }
        float ex = __expf(b1 - b0);
        float inv = 1.f / (1.f + ex);
        if (lane == 0) {
            int p0 = atomicAdd(&counts[e0], 1);
            ltok[e0 * NTOK + p0] = n; lwt[e0 * NTOK + p0] = inv;
            int p1 = atomicAdd(&counts[e1], 1);
            ltok[e1 * NTOK + p1] = n; lwt[e1 * NTOK + p1] = ex * inv;
        }
    }
}

// ---------------- pad lists up to multiple of BM with (token 0, weight 0) ----------------
__global__ void k_pad(const int* __restrict__ counts, int* __restrict__ ltok,
                      float* __restrict__ lwt) {
    int e = blockIdx.x;
    int c = counts[e];
    int cp = (c + BM - 1) & ~(BM - 1);
    for (int i = c + threadIdx.x; i < cp; i += blockDim.x) {
        ltok[e * NTOK + i] = 0;
        lwt[e * NTOK + i] = 0.f;
    }
}

// ---------------- grouped gathered GEMM: out[tok, :] += w * xb[tok,:] @ Wb_e^T ----------------
__global__ __launch_bounds__(256)
void k_gemm(const unsigned short* __restrict__ xb, const unsigned short* __restrict__ wb,
            const int* __restrict__ counts, const int* __restrict__ ltok,
            const float* __restrict__ lwt, float* __restrict__ out) {
    int e = blockIdx.z;
    int cnt = counts[e];
    int rb = blockIdx.y;
    if (rb * BM >= cnt) return;
    int cb = blockIdx.x;

    __shared__ unsigned short As[BM * BK];   // 16 KB, row-major [row][64]
    __shared__ unsigned short Bs[BN * BK];   // 16 KB
    __shared__ int   tokS[BM];
    __shared__ float wS[BM];

    int t = threadIdx.x;
    int lane = t & 63, wave = t >> 6;
    int wr = wave >> 1, wc = wave & 1;

    if (t < BM) {
        tokS[t] = ltok[e * NTOK + rb * BM + t];
        wS[t]   = lwt[e * NTOK + rb * BM + t];
    }

    const unsigned short* aSrc[4];
    const unsigned short* bSrc[4];
#pragma unroll
    for (int i = 0; i < 4; ++i) {
        int idx = i * 256 + t;          // 16B chunk index in the 128x64 tile
        int r   = idx >> 3;             // row 0..127
        int c8  = (idx & 7) * 8;        // col in elems
        int tok = ltok[e * NTOK + rb * BM + r];
        aSrc[i] = xb + (size_t)tok * NEMB + c8;
        bSrc[i] = wb + (size_t)e * NEMB * NEMB + (size_t)(cb * BN + r) * NEMB + c8;
    }

    f32x4 acc[4][4];
#pragma unroll
    for (int m = 0; m < 4; ++m)
#pragma unroll
        for (int n = 0; n < 4; ++n) acc[m][n] = (f32x4){0.f, 0.f, 0.f, 0.f};

    int fr = lane & 15, fq = lane >> 4;
    const unsigned short* Abase = As + (wr * 64 + fr) * BK + fq * 8;
    const unsigned short* Bbase = Bs + (wc * 64 + fr) * BK + fq * 8;

    for (int kk = 0; kk < NEMB / BK; ++kk) {
#pragma unroll
        for (int i = 0; i < 4; ++i) {
            int ldso = (i * 256 + wave * 64) * 8;   // wave-uniform LDS elem offset
            __builtin_amdgcn_global_load_lds(
                (const __attribute__((address_space(1))) void*)(aSrc[i]),
                (__attribute__((address_space(3))) void*)(As + ldso), 16, 0, 0);
            __builtin_amdgcn_global_load_lds(
                (const __attribute__((address_space(1))) void*)(bSrc[i]),
                (__attribute__((address_space(3))) void*)(Bs + ldso), 16, 0, 0);
        }
        __syncthreads();
#pragma unroll
        for (int ks = 0; ks < 2; ++ks) {
            bf16x8 af[4], bfr[4];
#pragma unroll
            for (int m = 0; m < 4; ++m)
                af[m] = *reinterpret_cast<const bf16x8*>(Abase + m * 16 * BK + ks * 32);
#pragma unroll
            for (int n = 0; n < 4; ++n)
                bfr[n] = *reinterpret_cast<const bf16x8*>(Bbase + n * 16 * BK + ks * 32);
#pragma unroll
            for (int m = 0; m < 4; ++m)
#pragma unroll
                for (int n = 0; n < 4; ++n)
                    acc[m][n] = __builtin_amdgcn_mfma_f32_16x16x32_bf16(
                        af[m], bfr[n], acc[m][n], 0, 0, 0);
        }
        __syncthreads();
#pragma unroll
        for (int i = 0; i < 4; ++i) { aSrc[i] += BK; bSrc[i] += BK; }
    }

#pragma unroll
    for (int m = 0; m < 4; ++m) {
#pragma unroll
        for (int jj = 0; jj < 4; ++jj) {
            int row  = wr * 64 + m * 16 + fq * 4 + jj;
            int tok  = tokS[row];
            float wgt = wS[row];
            float* orow = out + (size_t)tok * NEMB + cb * BN + wc * 64 + fr;
#pragma unroll
            for (int n = 0; n < 4; ++n)
                unsafeAtomicAdd(orow + n * 16, wgt * acc[m][n][jj]);
        }
    }
}

extern "C" void kernel_launch(void* const* d_in, const int* in_sizes, int n_in,
                              void* d_out, int out_size, void* d_ws, size_t ws_size,
                              hipStream_t stream) {
    const float* x  = (const float*)d_in[0];
    const float* gw = (const float*)d_in[1];
    const float* ew = (const float*)d_in[2];
    float* out = (float*)d_out;

    char* ws = (char*)d_ws;
    unsigned short* xb  = (unsigned short*)(ws);
    unsigned short* wb  = (unsigned short*)(ws + XB_BYTES);
    int*   counts = (int*)(ws + CNT_OFF);
    int*   ltok   = (int*)(ws + LTOK_OFF);
    float* lwt    = (float*)(ws + LWT_OFF);

    hipMemsetAsync(counts, 0, 8 * sizeof(int), stream);
    hipMemsetAsync(out, 0, (size_t)NTOK * NEMB * sizeof(float), stream);

    k_cvt_w<<<4096, 256, 0, stream>>>(ew, wb);
    k_gate<<<512, 256, 0, stream>>>(x, gw, xb, counts, ltok, lwt);
    k_pad<<<8, 128, 0, stream>>>(counts, ltok, lwt);
    k_gemm<<<dim3(NEMB / BN, NTOK / BM, NEXP), 256, 0, stream>>>(xb, wb, counts, ltok, lwt, out);
}

// Round 3
// 188.852 us; speedup vs baseline: 1.9192x; 1.8705x over previous
//
#include <hip/hip_runtime.h>
#include <hip/hip_bf16.h>

#define NEXP 8
#define NEMB 1024
#define NTOK 8192
#define BM 128
#define BN 128
#define BK 64
#define BLD_STRIPE 512

typedef __attribute__((ext_vector_type(8))) short  bf16x8;
typedef __attribute__((ext_vector_type(8))) unsigned short u16x8;
typedef __attribute__((ext_vector_type(4))) float  f32x4;

// ---- workspace layout (bytes) ----
#define XB_BYTES  (NTOK * NEMB * 2)
#define WB_BYTES  (NEXP * NEMB * NEMB * 2)
#define CNT_OFF   (XB_BYTES + WB_BYTES)
#define LTOK_OFF  (CNT_OFF + 256)
#define LWT_OFF   (LTOK_OFF + NEXP * NTOK * 4)
#define SELW_OFF  (LWT_OFF + NEXP * NTOK * 4)

__device__ __forceinline__ unsigned short f2bf(float f) {
    unsigned u = __builtin_bit_cast(unsigned, f);
    unsigned r = (u + 0x7fffu + ((u >> 16) & 1u)) >> 16;
    return (unsigned short)r;
}

// ---------------- expert_w fp32 -> bf16 ----------------
__global__ void k_cvt_w(const float* __restrict__ w, unsigned short* __restrict__ wb) {
    int i = (blockIdx.x * blockDim.x + threadIdx.x) * 8;
    f32x4 v0 = *reinterpret_cast<const f32x4*>(w + i);
    f32x4 v1 = *reinterpret_cast<const f32x4*>(w + i + 4);
    u16x8 o;
#pragma unroll
    for (int j = 0; j < 4; ++j) { o[j] = f2bf(v0[j]); o[4 + j] = f2bf(v1[j]); }
    *reinterpret_cast<u16x8*>(wb + i) = o;
}

// ---------------- gating: pure streaming, no atomics ----------------
// one token per wave; writes (e0,e1,w0,w1) per token + x->bf16
__global__ __launch_bounds__(256)
void k_gate(const float* __restrict__ x, const float* __restrict__ gw,
            unsigned short* __restrict__ xb, int4* __restrict__ selw) {
    int t = threadIdx.x, wave = t >> 6, lane = t & 63;
    int n = blockIdx.x * 4 + wave;

    const float* xr = x + (size_t)n * NEMB + lane * 16;
    f32x4 xv[4];
#pragma unroll
    for (int j = 0; j < 4; ++j) xv[j] = *reinterpret_cast<const f32x4*>(xr + j * 4);

    // x -> bf16 (two 16B stores per lane)
    u16x8 o0, o1;
#pragma unroll
    for (int q = 0; q < 4; ++q) {
        o0[q] = f2bf(xv[0][q]); o0[4 + q] = f2bf(xv[1][q]);
        o1[q] = f2bf(xv[2][q]); o1[4 + q] = f2bf(xv[3][q]);
    }
    u16x8* xo = reinterpret_cast<u16x8*>(xb + (size_t)n * NEMB + lane * 16);
    xo[0] = o0; xo[1] = o1;

    // logits: gate rows streamed from L2 per token (no register residency)
    float p[NEXP];
#pragma unroll
    for (int e = 0; e < NEXP; ++e) {
        const float* gr = gw + e * NEMB + lane * 16;
        f32x4 a = xv[0] * *reinterpret_cast<const f32x4*>(gr);
#pragma unroll
        for (int j = 1; j < 4; ++j) a += xv[j] * *reinterpret_cast<const f32x4*>(gr + j * 4);
        p[e] = a[0] + a[1] + a[2] + a[3];
    }
#pragma unroll
    for (int e = 0; e < NEXP; ++e) {
        float v = p[e];
#pragma unroll
        for (int m = 1; m < 64; m <<= 1) v += __shfl_xor(v, m, 64);
        p[e] = v;
    }
    if (lane == 0) {
        int e0 = 0; float b0 = p[0];
#pragma unroll
        for (int e = 1; e < NEXP; ++e) if (p[e] > b0) { b0 = p[e]; e0 = e; }
        int e1 = -1; float b1 = -3.4e38f;
#pragma unroll
        for (int e = 0; e < NEXP; ++e) if (e != e0 && p[e] > b1) { b1 = p[e]; e1 = e; }
        float ex = __expf(b1 - b0);
        float inv = 1.f / (1.f + ex);
        int4 s;
        s.x = e0; s.y = e1;
        s.z = __float_as_int(inv); s.w = __float_as_int(ex * inv);
        selw[n] = s;
    }
}

// ---------------- build per-expert token lists: LDS atomics, 1 global atomic/block ----------------
__global__ __launch_bounds__(256)
void k_build(const int4* __restrict__ selw, int* __restrict__ counts,
             int* __restrict__ ltok, float* __restrict__ lwt) {
    int e = blockIdx.y;
    int n0 = blockIdx.x * BLD_STRIPE;
    __shared__ int lcnt, base;
    __shared__ int   toks[BLD_STRIPE];
    __shared__ float wts[BLD_STRIPE];
    if (threadIdx.x == 0) lcnt = 0;
    __syncthreads();
    for (int i = threadIdx.x; i < BLD_STRIPE; i += 256) {
        int4 s = selw[n0 + i];
        if (s.x == e) {
            int p = atomicAdd(&lcnt, 1);
            toks[p] = n0 + i; wts[p] = __int_as_float(s.z);
        } else if (s.y == e) {
            int p = atomicAdd(&lcnt, 1);
            toks[p] = n0 + i; wts[p] = __int_as_float(s.w);
        }
    }
    __syncthreads();
    if (threadIdx.x == 0) base = atomicAdd(&counts[e], lcnt);
    __syncthreads();
    for (int i = threadIdx.x; i < lcnt; i += 256) {
        ltok[e * NTOK + base + i] = toks[i];
        lwt[e * NTOK + base + i]  = wts[i];
    }
}

// ---------------- pad lists up to multiple of BM with (token 0, weight 0) ----------------
__global__ void k_pad(const int* __restrict__ counts, int* __restrict__ ltok,
                      float* __restrict__ lwt) {
    int e = blockIdx.x;
    int c = counts[e];
    int cp = (c + BM - 1) & ~(BM - 1);
    for (int i = c + threadIdx.x; i < cp; i += blockDim.x) {
        ltok[e * NTOK + i] = 0;
        lwt[e * NTOK + i] = 0.f;
    }
}

// ---------------- grouped gathered GEMM: out[tok, :] += w * xb[tok,:] @ Wb_e^T ----------------
__global__ __launch_bounds__(256)
void k_gemm(const unsigned short* __restrict__ xb, const unsigned short* __restrict__ wb,
            const int* __restrict__ counts, const int* __restrict__ ltok,
            const float* __restrict__ lwt, float* __restrict__ out) {
    int e = blockIdx.z;
    int cnt = counts[e];
    int rb = blockIdx.y;
    if (rb * BM >= cnt) return;
    int cb = blockIdx.x;

    __shared__ unsigned short As[BM * BK];
    __shared__ unsigned short Bs[BN * BK];
    __shared__ int   tokS[BM];
    __shared__ float wS[BM];

    int t = threadIdx.x;
    int lane = t & 63, wave = t >> 6;
    int wr = wave >> 1, wc = wave & 1;

    if (t < BM) {
        tokS[t] = ltok[e * NTOK + rb * BM + t];
        wS[t]   = lwt[e * NTOK + rb * BM + t];
    }

    const unsigned short* aSrc[4];
    const unsigned short* bSrc[4];
#pragma unroll
    for (int i = 0; i < 4; ++i) {
        int idx = i * 256 + t;
        int r   = idx >> 3;
        int c8  = (idx & 7) * 8;
        int tok = ltok[e * NTOK + rb * BM + r];
        aSrc[i] = xb + (size_t)tok * NEMB + c8;
        bSrc[i] = wb + (size_t)e * NEMB * NEMB + (size_t)(cb * BN + r) * NEMB + c8;
    }

    f32x4 acc[4][4];
#pragma unroll
    for (int m = 0; m < 4; ++m)
#pragma unroll
        for (int n = 0; n < 4; ++n) acc[m][n] = (f32x4){0.f, 0.f, 0.f, 0.f};

    int fr = lane & 15, fq = lane >> 4;
    const unsigned short* Abase = As + (wr * 64 + fr) * BK + fq * 8;
    const unsigned short* Bbase = Bs + (wc * 64 + fr) * BK + fq * 8;

    for (int kk = 0; kk < NEMB / BK; ++kk) {
#pragma unroll
        for (int i = 0; i < 4; ++i) {
            int ldso = (i * 256 + wave * 64) * 8;
            __builtin_amdgcn_global_load_lds(
                (const __attribute__((address_space(1))) void*)(aSrc[i]),
                (__attribute__((address_space(3))) void*)(As + ldso), 16, 0, 0);
            __builtin_amdgcn_global_load_lds(
                (const __attribute__((address_space(1))) void*)(bSrc[i]),
                (__attribute__((address_space(3))) void*)(Bs + ldso), 16, 0, 0);
        }
        __syncthreads();
#pragma unroll
        for (int ks = 0; ks < 2; ++ks) {
            bf16x8 af[4], bfr[4];
#pragma unroll
            for (int m = 0; m < 4; ++m)
                af[m] = *reinterpret_cast<const bf16x8*>(Abase + m * 16 * BK + ks * 32);
#pragma unroll
            for (int n = 0; n < 4; ++n)
                bfr[n] = *reinterpret_cast<const bf16x8*>(Bbase + n * 16 * BK + ks * 32);
#pragma unroll
            for (int m = 0; m < 4; ++m)
#pragma unroll
                for (int n = 0; n < 4; ++n)
                    acc[m][n] = __builtin_amdgcn_mfma_f32_16x16x32_bf16(
                        af[m], bfr[n], acc[m][n], 0, 0, 0);
        }
        __syncthreads();
#pragma unroll
        for (int i = 0; i < 4; ++i) { aSrc[i] += BK; bSrc[i] += BK; }
    }

#pragma unroll
    for (int m = 0; m < 4; ++m) {
#pragma unroll
        for (int jj = 0; jj < 4; ++jj) {
            int row  = wr * 64 + m * 16 + fq * 4 + jj;
            int tok  = tokS[row];
            float wgt = wS[row];
            float* orow = out + (size_t)tok * NEMB + cb * BN + wc * 64 + fr;
#pragma unroll
            for (int n = 0; n < 4; ++n)
                unsafeAtomicAdd(orow + n * 16, wgt * acc[m][n][jj]);
        }
    }
}

extern "C" void kernel_launch(void* const* d_in, const int* in_sizes, int n_in,
                              void* d_out, int out_size, void* d_ws, size_t ws_size,
                              hipStream_t stream) {
    const float* x  = (const float*)d_in[0];
    const float* gw = (const float*)d_in[1];
    const float* ew = (const float*)d_in[2];
    float* out = (float*)d_out;

    char* ws = (char*)d_ws;
    unsigned short* xb  = (unsigned short*)(ws);
    unsigned short* wb  = (unsigned short*)(ws + XB_BYTES);
    int*   counts = (int*)(ws + CNT_OFF);
    int*   ltok   = (int*)(ws + LTOK_OFF);
    float* lwt    = (float*)(ws + LWT_OFF);
    int4*  selw   = (int4*)(ws + SELW_OFF);

    hipMemsetAsync(counts, 0, 8 * sizeof(int), stream);
    hipMemsetAsync(out, 0, (size_t)NTOK * NEMB * sizeof(float), stream);

    k_cvt_w<<<4096, 256, 0, stream>>>(ew, wb);
    k_gate<<<NTOK / 4, 256, 0, stream>>>(x, gw, xb, selw);
    k_build<<<dim3(NTOK / BLD_STRIPE, NEXP), 256, 0, stream>>>(selw, counts, ltok, lwt);
    k_pad<<<8, 128, 0, stream>>>(counts, ltok, lwt);
    k_gemm<<<dim3(NEMB / BN, NTOK / BM, NEXP), 256, 0, stream>>>(xb, wb, counts, ltok, lwt, out);
}

// Round 4
// 184.904 us; speedup vs baseline: 1.9602x; 1.0214x over previous
//
#include <hip/hip_runtime.h>
#include <hip/hip_bf16.h>

#define NEXP 8
#define NEMB 1024
#define NTOK 8192
#define BM 128
#define BN 128
#define BK 64
#define NK  (NEMB / BK)
#define BLD_STRIPE 512

typedef __attribute__((ext_vector_type(8))) short  bf16x8;
typedef __attribute__((ext_vector_type(8))) unsigned short u16x8;
typedef __attribute__((ext_vector_type(4))) float  f32x4;

// ---- workspace layout (bytes) ----
#define XB_BYTES  (NTOK * NEMB * 2)
#define WB_BYTES  (NEXP * NEMB * NEMB * 2)
#define CNT_OFF   (XB_BYTES + WB_BYTES)
#define LTOK_OFF  (CNT_OFF + 256)
#define LWT_OFF   (LTOK_OFF + NEXP * NTOK * 4)
#define SELW_OFF  (LWT_OFF + NEXP * NTOK * 4)

__device__ __forceinline__ unsigned short f2bf(float f) {
    unsigned u = __builtin_bit_cast(unsigned, f);
    unsigned r = (u + 0x7fffu + ((u >> 16) & 1u)) >> 16;
    return (unsigned short)r;
}

// ---------------- expert_w fp32 -> bf16 ----------------
__global__ void k_cvt_w(const float* __restrict__ w, unsigned short* __restrict__ wb) {
    int i = (blockIdx.x * blockDim.x + threadIdx.x) * 8;
    f32x4 v0 = *reinterpret_cast<const f32x4*>(w + i);
    f32x4 v1 = *reinterpret_cast<const f32x4*>(w + i + 4);
    u16x8 o;
#pragma unroll
    for (int j = 0; j < 4; ++j) { o[j] = f2bf(v0[j]); o[4 + j] = f2bf(v1[j]); }
    *reinterpret_cast<u16x8*>(wb + i) = o;
}

// ---------------- gating: pure streaming, no atomics ----------------
__global__ __launch_bounds__(256)
void k_gate(const float* __restrict__ x, const float* __restrict__ gw,
            unsigned short* __restrict__ xb, int4* __restrict__ selw) {
    int t = threadIdx.x, wave = t >> 6, lane = t & 63;
    int n = blockIdx.x * 4 + wave;

    const float* xr = x + (size_t)n * NEMB + lane * 16;
    f32x4 xv[4];
#pragma unroll
    for (int j = 0; j < 4; ++j) xv[j] = *reinterpret_cast<const f32x4*>(xr + j * 4);

    u16x8 o0, o1;
#pragma unroll
    for (int q = 0; q < 4; ++q) {
        o0[q] = f2bf(xv[0][q]); o0[4 + q] = f2bf(xv[1][q]);
        o1[q] = f2bf(xv[2][q]); o1[4 + q] = f2bf(xv[3][q]);
    }
    u16x8* xo = reinterpret_cast<u16x8*>(xb + (size_t)n * NEMB + lane * 16);
    xo[0] = o0; xo[1] = o1;

    float p[NEXP];
#pragma unroll
    for (int e = 0; e < NEXP; ++e) {
        const float* gr = gw + e * NEMB + lane * 16;
        f32x4 a = xv[0] * *reinterpret_cast<const f32x4*>(gr);
#pragma unroll
        for (int j = 1; j < 4; ++j) a += xv[j] * *reinterpret_cast<const f32x4*>(gr + j * 4);
        p[e] = a[0] + a[1] + a[2] + a[3];
    }
#pragma unroll
    for (int e = 0; e < NEXP; ++e) {
        float v = p[e];
#pragma unroll
        for (int m = 1; m < 64; m <<= 1) v += __shfl_xor(v, m, 64);
        p[e] = v;
    }
    if (lane == 0) {
        int e0 = 0; float b0 = p[0];
#pragma unroll
        for (int e = 1; e < NEXP; ++e) if (p[e] > b0) { b0 = p[e]; e0 = e; }
        int e1 = -1; float b1 = -3.4e38f;
#pragma unroll
        for (int e = 0; e < NEXP; ++e) if (e != e0 && p[e] > b1) { b1 = p[e]; e1 = e; }
        float ex = __expf(b1 - b0);
        float inv = 1.f / (1.f + ex);
        int4 s;
        s.x = e0; s.y = e1;
        s.z = __float_as_int(inv); s.w = __float_as_int(ex * inv);
        selw[n] = s;
    }
}

// ---------------- build per-expert token lists ----------------
__global__ __launch_bounds__(256)
void k_build(const int4* __restrict__ selw, int* __restrict__ counts,
             int* __restrict__ ltok, float* __restrict__ lwt) {
    int e = blockIdx.y;
    int n0 = blockIdx.x * BLD_STRIPE;
    __shared__ int lcnt, base;
    __shared__ int   toks[BLD_STRIPE];
    __shared__ float wts[BLD_STRIPE];
    if (threadIdx.x == 0) lcnt = 0;
    __syncthreads();
    for (int i = threadIdx.x; i < BLD_STRIPE; i += 256) {
        int4 s = selw[n0 + i];
        if (s.x == e) {
            int p = atomicAdd(&lcnt, 1);
            toks[p] = n0 + i; wts[p] = __int_as_float(s.z);
        } else if (s.y == e) {
            int p = atomicAdd(&lcnt, 1);
            toks[p] = n0 + i; wts[p] = __int_as_float(s.w);
        }
    }
    __syncthreads();
    if (threadIdx.x == 0) base = atomicAdd(&counts[e], lcnt);
    __syncthreads();
    for (int i = threadIdx.x; i < lcnt; i += 256) {
        ltok[e * NTOK + base + i] = toks[i];
        lwt[e * NTOK + base + i]  = wts[i];
    }
}

// ---------------- pad lists up to multiple of BM ----------------
__global__ void k_pad(const int* __restrict__ counts, int* __restrict__ ltok,
                      float* __restrict__ lwt) {
    int e = blockIdx.x;
    int c = counts[e];
    int cp = (c + BM - 1) & ~(BM - 1);
    for (int i = c + threadIdx.x; i < cp; i += blockDim.x) {
        ltok[e * NTOK + i] = 0;
        lwt[e * NTOK + i] = 0.f;
    }
}

// ---------------- grouped gathered GEMM, 2-phase pipelined + XOR-swizzled LDS ----------------
// LDS layout: linear [row][64] per buffer; position (row, chunk c) holds global
// chunk c ^ (row&7)  (involution; source pre-swizzled, read swizzled — rule #21).
__global__ __launch_bounds__(256)
void k_gemm(const unsigned short* __restrict__ xb, const unsigned short* __restrict__ wb,
            const int* __restrict__ counts, const int* __restrict__ ltok,
            const float* __restrict__ lwt, float* __restrict__ out) {
    int e = blockIdx.z;
    int cnt = counts[e];
    int rb = blockIdx.y;
    if (rb * BM >= cnt) return;
    int cb = blockIdx.x;

    __shared__ unsigned short As[2][BM * BK];   // 2 x 16 KB
    __shared__ unsigned short Bs[2][BN * BK];   // 2 x 16 KB
    __shared__ int   tokS[BM];
    __shared__ float wS[BM];

    int t = threadIdx.x;
    int lane = t & 63, wave = t >> 6;
    int wr = wave >> 1, wc = wave & 1;

    if (t < BM) {
        tokS[t] = ltok[e * NTOK + rb * BM + t];
        wS[t]   = lwt[e * NTOK + rb * BM + t];
    }

    // staging sources: chunk (r, c) at LDS gets global chunk c ^ (r&7)
    const unsigned short* aSrc[4];
    const unsigned short* bSrc[4];
    int ldsOff[4];
#pragma unroll
    for (int i = 0; i < 4; ++i) {
        int idx = i * 256 + t;
        int r   = idx >> 3;
        int c   = idx & 7;
        int csw = c ^ (r & 7);
        int tok = ltok[e * NTOK + rb * BM + r];
        aSrc[i] = xb + (size_t)tok * NEMB + csw * 8;
        bSrc[i] = wb + (size_t)e * NEMB * NEMB + (size_t)(cb * BN + r) * NEMB + csw * 8;
        ldsOff[i] = (i * 256 + wave * 64) * 8;   // wave-uniform base (lane*16B added by HW)
    }

#define STAGE(buf, kk)                                                              \
    {                                                                               \
        _Pragma("unroll")                                                           \
        for (int i = 0; i < 4; ++i) {                                               \
            __builtin_amdgcn_global_load_lds(                                       \
                (const __attribute__((address_space(1))) void*)(aSrc[i] + (kk) * BK),\
                (__attribute__((address_space(3))) void*)(&As[buf][0] + ldsOff[i]), \
                16, 0, 0);                                                          \
            __builtin_amdgcn_global_load_lds(                                       \
                (const __attribute__((address_space(1))) void*)(bSrc[i] + (kk) * BK),\
                (__attribute__((address_space(3))) void*)(&Bs[buf][0] + ldsOff[i]), \
                16, 0, 0);                                                          \
        }                                                                           \
    }

    f32x4 acc[4][4];
#pragma unroll
    for (int m = 0; m < 4; ++m)
#pragma unroll
        for (int n = 0; n < 4; ++n) acc[m][n] = (f32x4){0.f, 0.f, 0.f, 0.f};

    int fr = lane & 15, fq = lane >> 4, fs = fr & 7;

    STAGE(0, 0);
    __syncthreads();

    for (int kk = 0; kk < NK; ++kk) {
        int cur = kk & 1;
        if (kk + 1 < NK) STAGE(cur ^ 1, kk + 1);   // issue next-tile loads early (T3 min)

#pragma unroll
        for (int ks = 0; ks < 2; ++ks) {
            bf16x8 af[4], bfr[4];
#pragma unroll
            for (int m = 0; m < 4; ++m) {
                int row = wr * 64 + m * 16 + fr;
                int ch  = (fq + 4 * ks) ^ fs;
                af[m] = *reinterpret_cast<const bf16x8*>(&As[cur][0] + row * BK + ch * 8);
            }
#pragma unroll
            for (int n = 0; n < 4; ++n) {
                int row = wc * 64 + n * 16 + fr;
                int ch  = (fq + 4 * ks) ^ fs;
                bfr[n] = *reinterpret_cast<const bf16x8*>(&Bs[cur][0] + row * BK + ch * 8);
            }
#pragma unroll
            for (int m = 0; m < 4; ++m)
#pragma unroll
                for (int n = 0; n < 4; ++n)
                    acc[m][n] = __builtin_amdgcn_mfma_f32_16x16x32_bf16(
                        af[m], bfr[n], acc[m][n], 0, 0, 0);
        }
        __syncthreads();   // drains vmcnt (next tile landed) + lgkm; protects buf reuse
    }
#undef STAGE

#pragma unroll
    for (int m = 0; m < 4; ++m) {
#pragma unroll
        for (int jj = 0; jj < 4; ++jj) {
            int row  = wr * 64 + m * 16 + fq * 4 + jj;
            int tok  = tokS[row];
            float wgt = wS[row];
            float* orow = out + (size_t)tok * NEMB + cb * BN + wc * 64 + fr;
#pragma unroll
            for (int n = 0; n < 4; ++n)
                unsafeAtomicAdd(orow + n * 16, wgt * acc[m][n][jj]);
        }
    }
}

extern "C" void kernel_launch(void* const* d_in, const int* in_sizes, int n_in,
                              void* d_out, int out_size, void* d_ws, size_t ws_size,
                              hipStream_t stream) {
    const float* x  = (const float*)d_in[0];
    const float* gw = (const float*)d_in[1];
    const float* ew = (const float*)d_in[2];
    float* out = (float*)d_out;

    char* ws = (char*)d_ws;
    unsigned short* xb  = (unsigned short*)(ws);
    unsigned short* wb  = (unsigned short*)(ws + XB_BYTES);
    int*   counts = (int*)(ws + CNT_OFF);
    int*   ltok   = (int*)(ws + LTOK_OFF);
    float* lwt    = (float*)(ws + LWT_OFF);
    int4*  selw   = (int4*)(ws + SELW_OFF);

    hipMemsetAsync(counts, 0, 8 * sizeof(int), stream);
    hipMemsetAsync(out, 0, (size_t)NTOK * NEMB * sizeof(float), stream);

    k_cvt_w<<<4096, 256, 0, stream>>>(ew, wb);
    k_gate<<<NTOK / 4, 256, 0, stream>>>(x, gw, xb, selw);
    k_build<<<dim3(NTOK / BLD_STRIPE, NEXP), 256, 0, stream>>>(selw, counts, ltok, lwt);
    k_pad<<<8, 128, 0, stream>>>(counts, ltok, lwt);
    k_gemm<<<dim3(NEMB / BN, NTOK / BM, NEXP), 256, 0, stream>>>(xb, wb, counts, ltok, lwt, out);
}